// Round 2
// baseline (642.517 us; speedup 1.0000x reference)
//
#include <hip/hip_runtime.h>
#include <hip/hip_fp16.h>

#define TNUM 2048
#define DIMS 1024
#define HIDS 4096
#define NEXP 8
#define NROUT 7
#define ALPHAF 2.0f

typedef __attribute__((ext_vector_type(4))) float floatx4;
typedef _Float16 half8 __attribute__((ext_vector_type(8)));
typedef unsigned short ushort_t;

static __device__ __forceinline__ ushort_t f2h(float f) {
    return __half_as_ushort(__float2half(f));
}

// pack two fp32 -> one u32 of 2 f16 (RNE, bit-identical to f2h pairs)
static __device__ __forceinline__ unsigned pk(float a, float b) {
    return (unsigned)f2h(a) | ((unsigned)f2h(b) << 16);
}

// async 16B global -> LDS. lds base wave-uniform; HW adds lane*16.
static __device__ __forceinline__ void async16(ushort_t* lds, const ushort_t* g) {
#if __has_builtin(__builtin_amdgcn_global_load_lds)
    __builtin_amdgcn_global_load_lds(
        (const __attribute__((address_space(1))) unsigned int*)g,
        (__attribute__((address_space(3))) unsigned int*)lds, 16, 0, 0);
#else
    int l = threadIdx.x & 63;
    *(uint4*)(lds + l * 8) = *(const uint4*)g;
#endif
}

// ---------------- router: fp32 logits, softmax, top-1 ----------------
// best==7 (no routed expert) -> expert 0 with weight 0, so every token is in
// exactly one routed group (single-write down pass).
__global__ __launch_bounds__(256) void router_kernel(
    const float* __restrict__ x, const float* __restrict__ wr,
    int* __restrict__ idx, float* __restrict__ wtok)
{
    int tok = blockIdx.x * 4 + (threadIdx.x >> 6);
    int lane = threadIdx.x & 63;
    const float* xp = x + (size_t)tok * DIMS;
    float acc[NEXP];
#pragma unroll
    for (int e = 0; e < NEXP; ++e) acc[e] = 0.f;
    for (int d = lane; d < DIMS; d += 64) {
        float xv = xp[d];
        const float* wrow = wr + d * NEXP;
#pragma unroll
        for (int e = 0; e < NEXP; ++e) acc[e] += xv * wrow[e];
    }
#pragma unroll
    for (int off = 32; off > 0; off >>= 1) {
#pragma unroll
        for (int e = 0; e < NEXP; ++e) acc[e] += __shfl_xor(acc[e], off, 64);
    }
    if (lane == 0) {
        float mx = acc[0];
#pragma unroll
        for (int e = 1; e < NEXP; ++e) mx = fmaxf(mx, acc[e]);
        float s = 0.f, pe[NEXP];
#pragma unroll
        for (int e = 0; e < NEXP; ++e) { pe[e] = __expf(acc[e] - mx); s += pe[e]; }
        int best = 0; float bv = acc[0];
#pragma unroll
        for (int e = 1; e < NEXP; ++e) if (acc[e] > bv) { bv = acc[e]; best = e; }
        if (best == NROUT) { idx[tok] = 0; wtok[tok] = 0.f; }
        else               { idx[tok] = best; wtok[tok] = ALPHAF * pe[best] / s; }
    }
}

__global__ void zero_counts_kernel(int* counts) {
    if (threadIdx.x < NROUT) counts[threadIdx.x] = 0;
}

__global__ __launch_bounds__(256) void build_lists_kernel(
    const int* __restrict__ idx, int* __restrict__ counts, int* __restrict__ lists)
{
    int t = blockIdx.x * 256 + threadIdx.x;
    int e = idx[t];
    int pos = atomicAdd(&counts[e], 1);
    lists[e * TNUM + pos] = t;
}

// ---------------- x fp32 -> f16 ----------------
__global__ __launch_bounds__(256) void x2h_kernel(
    const float* __restrict__ x, ushort_t* __restrict__ x16)
{
    int i = (blockIdx.x * 256 + threadIdx.x) * 4;
    float4 v = *(const float4*)(x + i);
    ushort_t tmp[4] = { f2h(v.x), f2h(v.y), f2h(v.z), f2h(v.w) };
    *(uint2*)(x16 + i) = *(const uint2*)tmp;
}

// ---------------- weight repack: f32 [K][N] -> f16 [R(n)][K] ----------------
// up/gate rows per 64-group G: G*64+0..31 = up cols G*32+.., G*64+32..63 =
// gate cols. down: plain [n][k]. Expert 7 = shared.
//
// No-LDS version. Column reads: lane i reads src[k*N + n0+i] -> every load
// instruction is 64 consecutive dwords (256B, fully coalesced). Each thread
// owns 32 consecutive k at one n, packs pairs in-register (its own k-axis,
// no cross-lane), writes its 64B run of the dst row with 4x dwordx4.
// No LDS, no barrier -> occupancy bounded only by VGPR; >=8 loads in
// flight/thread. Adjacent waves cover adjacent 32-k chunks so each 128B dst
// line is completed by temporally-adjacent waves. Nontemporal loads keep the
// single-use fp32 stream out of L3 so the f16 outputs (192 MB) stay resident
// for the GEMMs.
// Block tile: 64 n x 128 k. Grid: 16*64*8 = 8192 ug + 8*16*32 = 4096 down.
__global__ __launch_bounds__(256) void repack_kernel(
    const float* __restrict__ wu, const float* __restrict__ wg, const float* __restrict__ wd,
    const float* __restrict__ su, const float* __restrict__ sg, const float* __restrict__ sd,
    ushort_t* __restrict__ wugT, ushort_t* __restrict__ wdT)
{
    int g = blockIdx.x;
    const float* src; ushort_t* dst; int N, K, gateAdd; bool ug;
    int nb, kb;
    if (g < 8192) {                          // up/gate: K=1024 (8 kb), N=4096 (64 nb)
        int slice = g >> 9, r = g & 511;
        nb = r & 63; kb = r >> 6;
        K = DIMS; N = HIDS; ug = true;
        if (slice < 7)        { src = wu + (size_t)slice * DIMS * HIDS;       dst = wugT + (size_t)slice * 2 * HIDS * DIMS; gateAdd = 0; }
        else if (slice < 14)  { src = wg + (size_t)(slice - 7) * DIMS * HIDS; dst = wugT + (size_t)(slice - 7) * 2 * HIDS * DIMS; gateAdd = 32; }
        else if (slice == 14) { src = su; dst = wugT + (size_t)7 * 2 * HIDS * DIMS; gateAdd = 0; }
        else                  { src = sg; dst = wugT + (size_t)7 * 2 * HIDS * DIMS; gateAdd = 32; }
    } else {                                 // down: K=4096 (32 kb), N=1024 (16 nb)
        int gd = g - 8192; int slice = gd >> 9, r = gd & 511;
        nb = r & 15; kb = r >> 4;
        K = HIDS; N = DIMS; ug = false; gateAdd = 0;
        if (slice < 7) { src = wd + (size_t)slice * HIDS * DIMS; dst = wdT + (size_t)slice * DIMS * HIDS; }
        else           { src = sd;                               dst = wdT + (size_t)7 * DIMS * HIDS; }
    }
    int n0 = nb * 64, k0 = kb * 128;

    int lane = threadIdx.x & 63, wv = threadIdx.x >> 6;
    int n = n0 + lane;
    int kbase = k0 + wv * 32;                // thread covers k [kbase, kbase+32)
    const float* sp = src + (size_t)kbase * N + n;
    size_t R = ug ? (size_t)(((n >> 5) << 6) + (n & 31) + gateAdd) : (size_t)n;
    ushort_t* dp = dst + R * (size_t)K + kbase;

#pragma unroll
    for (int gq = 0; gq < 4; ++gq) {         // 4 groups of 8 k -> 4x 16B stores
        float v[8];
#pragma unroll
        for (int j = 0; j < 8; ++j)
            v[j] = __builtin_nontemporal_load(sp + (size_t)(gq * 8 + j) * N);
        unsigned u[4] = { pk(v[0], v[1]), pk(v[2], v[3]),
                          pk(v[4], v[5]), pk(v[6], v[7]) };
        *(uint4*)(dp + gq * 8) = *(const uint4*)u;
    }
}

// ---------------- up/gate GEMM 128x128, BK=64, swizzled LDS ----------------
// z = expert (7 = shared over all tokens). h = [wtok *] u*silu(g) ->
// hcat[tok][8192]: shared half [0,4096), routed half [4096,8192).
__global__ __launch_bounds__(256) void upgate_gemm(
    const ushort_t* __restrict__ x16, const ushort_t* __restrict__ wugT,
    ushort_t* __restrict__ hcat,
    const int* __restrict__ lists, const int* __restrict__ counts,
    const float* __restrict__ wtok)
{
    int e = blockIdx.z;
    bool routed = e < NROUT;
    int cnt = routed ? counts[e] : TNUM;
    int m0 = blockIdx.y * 128;
    if (m0 >= cnt) return;
    int n0 = blockIdx.x * 128;
    const ushort_t* B = wugT + (size_t)e * 2 * HIDS * DIMS;

    __shared__ ushort_t As[128 * 64];
    __shared__ ushort_t Bs[128 * 64];
    __shared__ int rowTok[128];
    int t = threadIdx.x;
    if (t < 128) {
        int i = m0 + t;
        rowTok[t] = (i < cnt) ? (routed ? lists[e * TNUM + i] : i) : -1;
    }
    __syncthreads();

    int w = t >> 6, l = t & 63;
    const ushort_t *gA[4], *gB[4]; ushort_t *lA[4], *lB[4];
#pragma unroll
    for (int p = 0; p < 4; ++p) {
        int slot = p * 256 + t, row = slot >> 3, ch = (slot & 7) ^ (row & 7);
        int tok = rowTok[row]; if (tok < 0) tok = 0;
        gA[p] = x16 + (size_t)tok * DIMS + ch * 8;
        gB[p] = B + (size_t)(n0 + row) * DIMS + ch * 8;
        lA[p] = &As[(p * 256 + w * 64) * 8];
        lB[p] = &Bs[(p * 256 + w * 64) * 8];
    }

    floatx4 acc[4][4];
#pragma unroll
    for (int i = 0; i < 4; ++i)
#pragma unroll
        for (int j = 0; j < 4; ++j) acc[i][j] = (floatx4){0.f, 0.f, 0.f, 0.f};

    int wr = (w >> 1) * 64, wc = (w & 1) * 64;
    int fr = l & 15, fq = l >> 4;

    for (int k0 = 0; k0 < DIMS; k0 += 64) {
#pragma unroll
        for (int p = 0; p < 4; ++p) {
            async16(lA[p], gA[p]); gA[p] += 64;
            async16(lB[p], gB[p]); gB[p] += 64;
        }
        __syncthreads();
#pragma unroll
        for (int kk = 0; kk < 2; ++kk) {
            int gc = kk * 4 + fq;
            half8 a[4], b[4];
#pragma unroll
            for (int i = 0; i < 4; ++i) {
                int r = wr + i * 16 + fr;
                a[i] = *(const half8*)&As[r * 64 + ((gc ^ (r & 7)) << 3)];
            }
#pragma unroll
            for (int j = 0; j < 4; ++j) {
                int r = wc + j * 16 + fr;
                b[j] = *(const half8*)&Bs[r * 64 + ((gc ^ (r & 7)) << 3)];
            }
#pragma unroll
            for (int i = 0; i < 4; ++i)
#pragma unroll
                for (int j = 0; j < 4; ++j)
                    acc[i][j] = __builtin_amdgcn_mfma_f32_16x16x32_f16(a[i], b[j], acc[i][j], 0, 0, 0);
        }
        __syncthreads();
    }

    // epilogue: u at frag j, g at frag j+2 (same lane) -> no shuffles
    int cq = l & 15, rq = (l >> 4) * 4;
    int nbase = (n0 + wc) >> 1;
    size_t hoff = routed ? HIDS : 0;
#pragma unroll
    for (int i = 0; i < 4; ++i) {
#pragma unroll
        for (int r = 0; r < 4; ++r) {
            int m = wr + i * 16 + rq + r;
            int tok = rowTok[m];
            if (tok < 0) continue;
            float sc = routed ? wtok[tok] : 1.f;
            ushort_t* hp = hcat + (size_t)tok * (2 * HIDS) + hoff + nbase;
#pragma unroll
            for (int j = 0; j < 2; ++j) {
                float u = acc[i][j][r], gg = acc[i][j + 2][r];
                float h = sc * u * (gg / (1.f + __expf(-gg)));
                hp[j * 16 + cq] = f2h(h);
            }
        }
    }
}

// ---------------- down GEMM 128x128, split-K=4 over concat K=8192 ----------------
// z = e*4 + s. s=0,1 -> shared weight half, s=2,3 -> expert half.
// Writes fp32 partials part[s][tok][d]; reduce_kernel sums them.
__global__ __launch_bounds__(256) void down_gemm(
    const ushort_t* __restrict__ hcat, const ushort_t* __restrict__ wdT,
    float* __restrict__ part,
    const int* __restrict__ lists, const int* __restrict__ counts)
{
    int z = blockIdx.z;
    int e = z >> 2, s = z & 3;
    int cnt = counts[e];
    int m0 = blockIdx.y * 128;
    if (m0 >= cnt) return;
    int n0 = blockIdx.x * 128;
    const ushort_t* B = (s < 2)
        ? wdT + (size_t)NROUT * DIMS * HIDS + (size_t)s * 2048
        : wdT + (size_t)e * DIMS * HIDS + (size_t)(s - 2) * 2048;
    size_t aoff = (size_t)s * 2048;

    __shared__ ushort_t As[128 * 64];
    __shared__ ushort_t Bs[128 * 64];
    __shared__ int rowTok[128];
    int t = threadIdx.x;
    if (t < 128) {
        int i = m0 + t;
        rowTok[t] = (i < cnt) ? lists[e * TNUM + i] : -1;
    }
    __syncthreads();

    int w = t >> 6, l = t & 63;
    const ushort_t *gA[4], *gB[4]; ushort_t *lA[4], *lB[4];
#pragma unroll
    for (int p = 0; p < 4; ++p) {
        int slot = p * 256 + t, row = slot >> 3, ch = (slot & 7) ^ (row & 7);
        int tok = rowTok[row]; if (tok < 0) tok = 0;
        gA[p] = hcat + (size_t)tok * (2 * HIDS) + aoff + ch * 8;
        gB[p] = B + (size_t)(n0 + row) * HIDS + ch * 8;
        lA[p] = &As[(p * 256 + w * 64) * 8];
        lB[p] = &Bs[(p * 256 + w * 64) * 8];
    }

    floatx4 acc[4][4];
#pragma unroll
    for (int i = 0; i < 4; ++i)
#pragma unroll
        for (int j = 0; j < 4; ++j) acc[i][j] = (floatx4){0.f, 0.f, 0.f, 0.f};

    int wr = (w >> 1) * 64, wc = (w & 1) * 64;
    int fr = l & 15, fq = l >> 4;

    for (int k0 = 0; k0 < 2048; k0 += 64) {
#pragma unroll
        for (int p = 0; p < 4; ++p) {
            async16(lA[p], gA[p]); gA[p] += 64;
            async16(lB[p], gB[p]); gB[p] += 64;
        }
        __syncthreads();
#pragma unroll
        for (int kk = 0; kk < 2; ++kk) {
            int gc = kk * 4 + fq;
            half8 a[4], b[4];
#pragma unroll
            for (int i = 0; i < 4; ++i) {
                int r = wr + i * 16 + fr;
                a[i] = *(const half8*)&As[r * 64 + ((gc ^ (r & 7)) << 3)];
            }
#pragma unroll
            for (int j = 0; j < 4; ++j) {
                int r = wc + j * 16 + fr;
                b[j] = *(const half8*)&Bs[r * 64 + ((gc ^ (r & 7)) << 3)];
            }
#pragma unroll
            for (int i = 0; i < 4; ++i)
#pragma unroll
                for (int j = 0; j < 4; ++j)
                    acc[i][j] = __builtin_amdgcn_mfma_f32_16x16x32_f16(a[i], b[j], acc[i][j], 0, 0, 0);
        }
        __syncthreads();
    }

    int cq = l & 15, rq = (l >> 4) * 4;
#pragma unroll
    for (int i = 0; i < 4; ++i) {
#pragma unroll
        for (int r = 0; r < 4; ++r) {
            int m = wr + i * 16 + rq + r;
            int tok = rowTok[m];
            if (tok < 0) continue;
            float* pp = part + ((size_t)s * TNUM + tok) * DIMS + n0 + wc;
#pragma unroll
            for (int j = 0; j < 4; ++j) pp[j * 16 + cq] = acc[i][j][r];
        }
    }
}

// ---------------- reduce: out = sum of 4 partials ----------------
__global__ __launch_bounds__(256) void reduce_kernel(
    const float* __restrict__ part, float* __restrict__ out)
{
    size_t i = ((size_t)blockIdx.x * 256 + threadIdx.x) * 4;
    float4 a = *(const float4*)(part + i);
    float4 b = *(const float4*)(part + (size_t)TNUM * DIMS + i);
    float4 c = *(const float4*)(part + (size_t)2 * TNUM * DIMS + i);
    float4 d = *(const float4*)(part + (size_t)3 * TNUM * DIMS + i);
    float4 o = make_float4(a.x + b.x + c.x + d.x, a.y + b.y + c.y + d.y,
                           a.z + b.z + c.z + d.z, a.w + b.w + c.w + d.w);
    *(float4*)(out + i) = o;
}

extern "C" void kernel_launch(void* const* d_in, const int* in_sizes, int n_in,
                              void* d_out, int out_size, void* d_ws, size_t ws_size,
                              hipStream_t stream)
{
    const float* x  = (const float*)d_in[0];
    const float* wr = (const float*)d_in[1];
    const float* wu = (const float*)d_in[2];
    const float* wg = (const float*)d_in[3];
    const float* wd = (const float*)d_in[4];
    const float* su = (const float*)d_in[5];
    const float* sg = (const float*)d_in[6];
    const float* sd = (const float*)d_in[7];
    float* out = (float*)d_out;

    char* ws = (char*)d_ws;
    size_t off = 0;
    ushort_t* wugT = (ushort_t*)(ws + off); off += (size_t)NEXP * 2 * HIDS * DIMS * 2;  // 128 MB
    ushort_t* wdT  = (ushort_t*)(ws + off); off += (size_t)NEXP * DIMS * HIDS * 2;      //  64 MB
    ushort_t* x16  = (ushort_t*)(ws + off); off += (size_t)TNUM * DIMS * 2;             //   4 MB
    ushort_t* hcat = (ushort_t*)(ws + off); off += (size_t)TNUM * 2 * HIDS * 2;         //  32 MB
    float* part    = (float*)(ws + off);    off += (size_t)4 * TNUM * DIMS * 4;         //  32 MB
    float* wtok    = (float*)(ws + off);    off += TNUM * 4;
    int* idx       = (int*)(ws + off);      off += TNUM * 4;
    int* counts    = (int*)(ws + off);      off += 64;
    int* lists     = (int*)(ws + off);      off += (size_t)NROUT * TNUM * 4;

    router_kernel<<<TNUM / 4, 256, 0, stream>>>(x, wr, idx, wtok);
    zero_counts_kernel<<<1, 64, 0, stream>>>(counts);
    build_lists_kernel<<<TNUM / 256, 256, 0, stream>>>(idx, counts, lists);
    x2h_kernel<<<TNUM * DIMS / 1024, 256, 0, stream>>>(x, x16);
    repack_kernel<<<12288, 256, 0, stream>>>(wu, wg, wd, su, sg, sd, wugT, wdT);

    upgate_gemm<<<dim3(2 * HIDS / 128, TNUM / 128, NEXP), 256, 0, stream>>>(
        x16, wugT, hcat, lists, counts, wtok);
    down_gemm<<<dim3(DIMS / 128, TNUM / 128, NROUT * 4), 256, 0, stream>>>(
        hcat, wdT, part, lists, counts);
    reduce_kernel<<<TNUM * DIMS / 1024, 256, 0, stream>>>(part, out);
}

// Round 4
// 583.284 us; speedup vs baseline: 1.1016x; 1.1016x over previous
//
#include <hip/hip_runtime.h>
#include <hip/hip_fp16.h>

#define TNUM 2048
#define DIMS 1024
#define HIDS 4096
#define NEXP 8
#define NROUT 7
#define ALPHAF 2.0f

typedef __attribute__((ext_vector_type(4))) float floatx4;
typedef _Float16 half8 __attribute__((ext_vector_type(8)));
typedef unsigned short ushort_t;

static __device__ __forceinline__ ushort_t f2h(float f) {
    return __half_as_ushort(__float2half(f));
}

// pack two fp32 -> one u32 of 2 f16 (RNE, bit-identical to f2h pairs)
static __device__ __forceinline__ unsigned pk(float a, float b) {
    return (unsigned)f2h(a) | ((unsigned)f2h(b) << 16);
}

// async 16B global -> LDS. lds base wave-uniform; HW adds lane*16.
static __device__ __forceinline__ void async16(ushort_t* lds, const ushort_t* g) {
#if __has_builtin(__builtin_amdgcn_global_load_lds)
    __builtin_amdgcn_global_load_lds(
        (const __attribute__((address_space(1))) unsigned int*)g,
        (__attribute__((address_space(3))) unsigned int*)lds, 16, 0, 0);
#else
    int l = threadIdx.x & 63;
    *(uint4*)(lds + l * 8) = *(const uint4*)g;
#endif
}

// ---------------- router: fp32 logits, softmax, top-1 ----------------
// best==7 (no routed expert) -> expert 0 with weight 0, so every token is in
// exactly one routed group (single-write down pass).
__global__ __launch_bounds__(256) void router_kernel(
    const float* __restrict__ x, const float* __restrict__ wr,
    int* __restrict__ idx, float* __restrict__ wtok)
{
    int tok = blockIdx.x * 4 + (threadIdx.x >> 6);
    int lane = threadIdx.x & 63;
    const float* xp = x + (size_t)tok * DIMS;
    float acc[NEXP];
#pragma unroll
    for (int e = 0; e < NEXP; ++e) acc[e] = 0.f;
    for (int d = lane; d < DIMS; d += 64) {
        float xv = xp[d];
        const float* wrow = wr + d * NEXP;
#pragma unroll
        for (int e = 0; e < NEXP; ++e) acc[e] += xv * wrow[e];
    }
#pragma unroll
    for (int off = 32; off > 0; off >>= 1) {
#pragma unroll
        for (int e = 0; e < NEXP; ++e) acc[e] += __shfl_xor(acc[e], off, 64);
    }
    if (lane == 0) {
        float mx = acc[0];
#pragma unroll
        for (int e = 1; e < NEXP; ++e) mx = fmaxf(mx, acc[e]);
        float s = 0.f, pe[NEXP];
#pragma unroll
        for (int e = 0; e < NEXP; ++e) { pe[e] = __expf(acc[e] - mx); s += pe[e]; }
        int best = 0; float bv = acc[0];
#pragma unroll
        for (int e = 1; e < NEXP; ++e) if (acc[e] > bv) { bv = acc[e]; best = e; }
        if (best == NROUT) { idx[tok] = 0; wtok[tok] = 0.f; }
        else               { idx[tok] = best; wtok[tok] = ALPHAF * pe[best] / s; }
    }
}

__global__ void zero_counts_kernel(int* counts) {
    if (threadIdx.x < NROUT) counts[threadIdx.x] = 0;
}

__global__ __launch_bounds__(256) void build_lists_kernel(
    const int* __restrict__ idx, int* __restrict__ counts, int* __restrict__ lists)
{
    int t = blockIdx.x * 256 + threadIdx.x;
    int e = idx[t];
    int pos = atomicAdd(&counts[e], 1);
    lists[e * TNUM + pos] = t;
}

// ---------------- x fp32 -> f16 ----------------
__global__ __launch_bounds__(256) void x2h_kernel(
    const float* __restrict__ x, ushort_t* __restrict__ x16)
{
    int i = (blockIdx.x * 256 + threadIdx.x) * 4;
    float4 v = *(const float4*)(x + i);
    ushort_t tmp[4] = { f2h(v.x), f2h(v.y), f2h(v.z), f2h(v.w) };
    *(uint2*)(x16 + i) = *(const uint2*)tmp;
}

// ---------------- weight repack: f32 [K][N] -> f16 [R(n)][K] ----------------
// up/gate rows per 64-group G: G*64+0..31 = up cols G*32+.., G*64+32..63 =
// gate cols. down: plain [n][k]. Expert 7 = shared.
//
// Per-instruction-granularity version. Tile 64n x 128k per block (256 thr).
// Phase A: thread = (k-oct, n-quad): 8 float4 NT loads; each load instr is
//   4 x 256B aligned row segments. pk pairs span all 8 loads -> compiler
//   cannot sink below 8 loads in flight.
// Phase B: per n (4/thread), one ds_write_b128 of 8 consecutive k. LDS tile
//   [64][136] (16B row pad) -> bank-quad (n + koct) mod 8, exactly 8
//   lanes/quad = b128 floor, no above-floor conflicts.
// Phase C: lanes along k: 16 lanes cover one dst row's 256B segment; each
//   store instr = 4 fully-written aligned 256B segments (8 whole lines) --
//   the float4-copy write shape -- instead of 64 partial-line touches.
// Grid: 16*64*8 = 8192 ug + 8*16*32 = 4096 down (kb fastest: adjacent
// blocks write adjacent 256B segments of the same rows).
__global__ __launch_bounds__(256) void repack_kernel(
    const float* __restrict__ wu, const float* __restrict__ wg, const float* __restrict__ wd,
    const float* __restrict__ su, const float* __restrict__ sg, const float* __restrict__ sd,
    ushort_t* __restrict__ wugT, ushort_t* __restrict__ wdT)
{
    int g = blockIdx.x;
    const float* src; ushort_t* dst; int N, K, gateAdd; bool ug;
    int nb, kb;
    if (g < 8192) {                          // up/gate: K=1024 (8 kb), N=4096 (64 nb)
        int slice = g >> 9, r = g & 511;
        nb = r >> 3; kb = r & 7;
        K = DIMS; N = HIDS; ug = true;
        if (slice < 7)        { src = wu + (size_t)slice * DIMS * HIDS;       dst = wugT + (size_t)slice * 2 * HIDS * DIMS; gateAdd = 0; }
        else if (slice < 14)  { src = wg + (size_t)(slice - 7) * DIMS * HIDS; dst = wugT + (size_t)(slice - 7) * 2 * HIDS * DIMS; gateAdd = 32; }
        else if (slice == 14) { src = su; dst = wugT + (size_t)7 * 2 * HIDS * DIMS; gateAdd = 0; }
        else                  { src = sg; dst = wugT + (size_t)7 * 2 * HIDS * DIMS; gateAdd = 32; }
    } else {                                 // down: K=4096 (32 kb), N=1024 (16 nb)
        int gd = g - 8192; int slice = gd >> 9, r = gd & 511;
        nb = r >> 5; kb = r & 31;
        K = HIDS; N = DIMS; ug = false; gateAdd = 0;
        if (slice < 7) { src = wd + (size_t)slice * HIDS * DIMS; dst = wdT + (size_t)slice * DIMS * HIDS; }
        else           { src = sd;                               dst = wdT + (size_t)7 * DIMS * HIDS; }
    }
    int n0 = nb * 64, k0 = kb * 128;

    __shared__ __align__(16) ushort_t T[64][136];   // [n][k], 16B row pad
    int t = threadIdx.x;
    int koct = t >> 4, nq = t & 15;          // k-oct 0..15 (8 k each), n-quad 0..15 (4 n each)

    // ---- phase A: 8 NT float4 loads (8 consecutive k rows, 4 consecutive n) ----
    const float* sp = src + (size_t)(k0 + koct * 8) * N + n0 + nq * 4;
    floatx4 a[8];
#pragma unroll
    for (int i = 0; i < 8; ++i)
        a[i] = __builtin_nontemporal_load((const floatx4*)(sp + (size_t)i * N));

    // ---- phase B: pk along k (spans all 8 loads), 4x ds_write_b128 ----
#pragma unroll
    for (int j = 0; j < 4; ++j) {
        unsigned u[4] = {
            pk(a[0][j], a[1][j]), pk(a[2][j], a[3][j]),
            pk(a[4][j], a[5][j]), pk(a[6][j], a[7][j]) };
        *(uint4*)&T[nq * 4 + j][koct * 8] = *(const uint4*)u;
    }
    __syncthreads();

    // ---- phase C: 16 lanes per dst row segment -> 4x 256B contiguous per instr ----
    int wv = t >> 6, l = t & 63;
    int c = l & 15, rof = l >> 4;
#pragma unroll
    for (int s = 0; s < 4; ++s) {
        int r = wv * 16 + s * 4 + rof;       // n-local row 0..63
        int n = n0 + r;
        size_t R = ug ? (size_t)(((n >> 5) << 6) + (n & 31) + gateAdd) : (size_t)n;
        ushort_t* dp = dst + R * (size_t)K + k0 + c * 8;
        *(uint4*)dp = *(const uint4*)&T[r][c * 8];
    }
}

// ---------------- up/gate GEMM 128x128, BK=64, swizzled LDS ----------------
// z = expert (7 = shared over all tokens). h = [wtok *] u*silu(g) ->
// hcat[tok][8192]: shared half [0,4096), routed half [4096,8192).
__global__ __launch_bounds__(256) void upgate_gemm(
    const ushort_t* __restrict__ x16, const ushort_t* __restrict__ wugT,
    ushort_t* __restrict__ hcat,
    const int* __restrict__ lists, const int* __restrict__ counts,
    const float* __restrict__ wtok)
{
    int e = blockIdx.z;
    bool routed = e < NROUT;
    int cnt = routed ? counts[e] : TNUM;
    int m0 = blockIdx.y * 128;
    if (m0 >= cnt) return;
    int n0 = blockIdx.x * 128;
    const ushort_t* B = wugT + (size_t)e * 2 * HIDS * DIMS;

    __shared__ ushort_t As[128 * 64];
    __shared__ ushort_t Bs[128 * 64];
    __shared__ int rowTok[128];
    int t = threadIdx.x;
    if (t < 128) {
        int i = m0 + t;
        rowTok[t] = (i < cnt) ? (routed ? lists[e * TNUM + i] : i) : -1;
    }
    __syncthreads();

    int w = t >> 6, l = t & 63;
    const ushort_t *gA[4], *gB[4]; ushort_t *lA[4], *lB[4];
#pragma unroll
    for (int p = 0; p < 4; ++p) {
        int slot = p * 256 + t, row = slot >> 3, ch = (slot & 7) ^ (row & 7);
        int tok = rowTok[row]; if (tok < 0) tok = 0;
        gA[p] = x16 + (size_t)tok * DIMS + ch * 8;
        gB[p] = B + (size_t)(n0 + row) * DIMS + ch * 8;
        lA[p] = &As[(p * 256 + w * 64) * 8];
        lB[p] = &Bs[(p * 256 + w * 64) * 8];
    }

    floatx4 acc[4][4];
#pragma unroll
    for (int i = 0; i < 4; ++i)
#pragma unroll
        for (int j = 0; j < 4; ++j) acc[i][j] = (floatx4){0.f, 0.f, 0.f, 0.f};

    int wr = (w >> 1) * 64, wc = (w & 1) * 64;
    int fr = l & 15, fq = l >> 4;

    for (int k0 = 0; k0 < DIMS; k0 += 64) {
#pragma unroll
        for (int p = 0; p < 4; ++p) {
            async16(lA[p], gA[p]); gA[p] += 64;
            async16(lB[p], gB[p]); gB[p] += 64;
        }
        __syncthreads();
#pragma unroll
        for (int kk = 0; kk < 2; ++kk) {
            int gc = kk * 4 + fq;
            half8 a[4], b[4];
#pragma unroll
            for (int i = 0; i < 4; ++i) {
                int r = wr + i * 16 + fr;
                a[i] = *(const half8*)&As[r * 64 + ((gc ^ (r & 7)) << 3)];
            }
#pragma unroll
            for (int j = 0; j < 4; ++j) {
                int r = wc + j * 16 + fr;
                b[j] = *(const half8*)&Bs[r * 64 + ((gc ^ (r & 7)) << 3)];
            }
#pragma unroll
            for (int i = 0; i < 4; ++i)
#pragma unroll
                for (int j = 0; j < 4; ++j)
                    acc[i][j] = __builtin_amdgcn_mfma_f32_16x16x32_f16(a[i], b[j], acc[i][j], 0, 0, 0);
        }
        __syncthreads();
    }

    // epilogue: u at frag j, g at frag j+2 (same lane) -> no shuffles
    int cq = l & 15, rq = (l >> 4) * 4;
    int nbase = (n0 + wc) >> 1;
    size_t hoff = routed ? HIDS : 0;
#pragma unroll
    for (int i = 0; i < 4; ++i) {
#pragma unroll
        for (int r = 0; r < 4; ++r) {
            int m = wr + i * 16 + rq + r;
            int tok = rowTok[m];
            if (tok < 0) continue;
            float sc = routed ? wtok[tok] : 1.f;
            ushort_t* hp = hcat + (size_t)tok * (2 * HIDS) + hoff + nbase;
#pragma unroll
            for (int j = 0; j < 2; ++j) {
                float u = acc[i][j][r], gg = acc[i][j + 2][r];
                float h = sc * u * (gg / (1.f + __expf(-gg)));
                hp[j * 16 + cq] = f2h(h);
            }
        }
    }
}

// ---------------- down GEMM 128x128, split-K=4 over concat K=8192 ----------------
// z = e*4 + s. s=0,1 -> shared weight half, s=2,3 -> expert half.
// Writes fp32 partials part[s][tok][d]; reduce_kernel sums them.
__global__ __launch_bounds__(256) void down_gemm(
    const ushort_t* __restrict__ hcat, const ushort_t* __restrict__ wdT,
    float* __restrict__ part,
    const int* __restrict__ lists, const int* __restrict__ counts)
{
    int z = blockIdx.z;
    int e = z >> 2, s = z & 3;
    int cnt = counts[e];
    int m0 = blockIdx.y * 128;
    if (m0 >= cnt) return;
    int n0 = blockIdx.x * 128;
    const ushort_t* B = (s < 2)
        ? wdT + (size_t)NROUT * DIMS * HIDS + (size_t)s * 2048
        : wdT + (size_t)e * DIMS * HIDS + (size_t)(s - 2) * 2048;
    size_t aoff = (size_t)s * 2048;

    __shared__ ushort_t As[128 * 64];
    __shared__ ushort_t Bs[128 * 64];
    __shared__ int rowTok[128];
    int t = threadIdx.x;
    if (t < 128) {
        int i = m0 + t;
        rowTok[t] = (i < cnt) ? lists[e * TNUM + i] : -1;
    }
    __syncthreads();

    int w = t >> 6, l = t & 63;
    const ushort_t *gA[4], *gB[4]; ushort_t *lA[4], *lB[4];
#pragma unroll
    for (int p = 0; p < 4; ++p) {
        int slot = p * 256 + t, row = slot >> 3, ch = (slot & 7) ^ (row & 7);
        int tok = rowTok[row]; if (tok < 0) tok = 0;
        gA[p] = hcat + (size_t)tok * (2 * HIDS) + aoff + ch * 8;
        gB[p] = B + (size_t)(n0 + row) * HIDS + ch * 8;
        lA[p] = &As[(p * 256 + w * 64) * 8];
        lB[p] = &Bs[(p * 256 + w * 64) * 8];
    }

    floatx4 acc[4][4];
#pragma unroll
    for (int i = 0; i < 4; ++i)
#pragma unroll
        for (int j = 0; j < 4; ++j) acc[i][j] = (floatx4){0.f, 0.f, 0.f, 0.f};

    int wr = (w >> 1) * 64, wc = (w & 1) * 64;
    int fr = l & 15, fq = l >> 4;

    for (int k0 = 0; k0 < 2048; k0 += 64) {
#pragma unroll
        for (int p = 0; p < 4; ++p) {
            async16(lA[p], gA[p]); gA[p] += 64;
            async16(lB[p], gB[p]); gB[p] += 64;
        }
        __syncthreads();
#pragma unroll
        for (int kk = 0; kk < 2; ++kk) {
            int gc = kk * 4 + fq;
            half8 a[4], b[4];
#pragma unroll
            for (int i = 0; i < 4; ++i) {
                int r = wr + i * 16 + fr;
                a[i] = *(const half8*)&As[r * 64 + ((gc ^ (r & 7)) << 3)];
            }
#pragma unroll
            for (int j = 0; j < 4; ++j) {
                int r = wc + j * 16 + fr;
                b[j] = *(const half8*)&Bs[r * 64 + ((gc ^ (r & 7)) << 3)];
            }
#pragma unroll
            for (int i = 0; i < 4; ++i)
#pragma unroll
                for (int j = 0; j < 4; ++j)
                    acc[i][j] = __builtin_amdgcn_mfma_f32_16x16x32_f16(a[i], b[j], acc[i][j], 0, 0, 0);
        }
        __syncthreads();
    }

    int cq = l & 15, rq = (l >> 4) * 4;
#pragma unroll
    for (int i = 0; i < 4; ++i) {
#pragma unroll
        for (int r = 0; r < 4; ++r) {
            int m = wr + i * 16 + rq + r;
            int tok = rowTok[m];
            if (tok < 0) continue;
            float* pp = part + ((size_t)s * TNUM + tok) * DIMS + n0 + wc;
#pragma unroll
            for (int j = 0; j < 4; ++j) pp[j * 16 + cq] = acc[i][j][r];
        }
    }
}

// ---------------- reduce: out = sum of 4 partials ----------------
__global__ __launch_bounds__(256) void reduce_kernel(
    const float* __restrict__ part, float* __restrict__ out)
{
    size_t i = ((size_t)blockIdx.x * 256 + threadIdx.x) * 4;
    float4 a = *(const float4*)(part + i);
    float4 b = *(const float4*)(part + (size_t)TNUM * DIMS + i);
    float4 c = *(const float4*)(part + (size_t)2 * TNUM * DIMS + i);
    float4 d = *(const float4*)(part + (size_t)3 * TNUM * DIMS + i);
    float4 o = make_float4(a.x + b.x + c.x + d.x, a.y + b.y + c.y + d.y,
                           a.z + b.z + c.z + d.z, a.w + b.w + c.w + d.w);
    *(float4*)(out + i) = o;
}

extern "C" void kernel_launch(void* const* d_in, const int* in_sizes, int n_in,
                              void* d_out, int out_size, void* d_ws, size_t ws_size,
                              hipStream_t stream)
{
    const float* x  = (const float*)d_in[0];
    const float* wr = (const float*)d_in[1];
    const float* wu = (const float*)d_in[2];
    const float* wg = (const float*)d_in[3];
    const float* wd = (const float*)d_in[4];
    const float* su = (const float*)d_in[5];
    const float* sg = (const float*)d_in[6];
    const float* sd = (const float*)d_in[7];
    float* out = (float*)d_out;

    char* ws = (char*)d_ws;
    size_t off = 0;
    ushort_t* wugT = (ushort_t*)(ws + off); off += (size_t)NEXP * 2 * HIDS * DIMS * 2;  // 128 MB
    ushort_t* wdT  = (ushort_t*)(ws + off); off += (size_t)NEXP * DIMS * HIDS * 2;      //  64 MB
    ushort_t* x16  = (ushort_t*)(ws + off); off += (size_t)TNUM * DIMS * 2;             //   4 MB
    ushort_t* hcat = (ushort_t*)(ws + off); off += (size_t)TNUM * 2 * HIDS * 2;         //  32 MB
    float* part    = (float*)(ws + off);    off += (size_t)4 * TNUM * DIMS * 4;         //  32 MB
    float* wtok    = (float*)(ws + off);    off += TNUM * 4;
    int* idx       = (int*)(ws + off);      off += TNUM * 4;
    int* counts    = (int*)(ws + off);      off += 64;
    int* lists     = (int*)(ws + off);      off += (size_t)NROUT * TNUM * 4;

    router_kernel<<<TNUM / 4, 256, 0, stream>>>(x, wr, idx, wtok);
    zero_counts_kernel<<<1, 64, 0, stream>>>(counts);
    build_lists_kernel<<<TNUM / 256, 256, 0, stream>>>(idx, counts, lists);
    x2h_kernel<<<TNUM * DIMS / 1024, 256, 0, stream>>>(x, x16);
    repack_kernel<<<12288, 256, 0, stream>>>(wu, wg, wd, su, sg, sd, wugT, wdT);

    upgate_gemm<<<dim3(2 * HIDS / 128, TNUM / 128, NEXP), 256, 0, stream>>>(
        x16, wugT, hcat, lists, counts, wtok);
    down_gemm<<<dim3(DIMS / 128, TNUM / 128, NROUT * 4), 256, 0, stream>>>(
        hcat, wdT, part, lists, counts);
    reduce_kernel<<<TNUM * DIMS / 1024, 256, 0, stream>>>(part, out);
}